// Round 5
// baseline (248.511 us; speedup 1.0000x reference)
//
#include <hip/hip_runtime.h>
#include <hip/hip_bf16.h>

// Problem constants
#define NE      1024
#define ED      64
#define ZTOT    2097152       // 32*64*1024

// d_out layout (floats): z_q_st[ZTOT], loss[1], sampled[32768], min_idx[32768]
#define OFF_LOSS 2097152
#define OFF_SAMP 2097153
#define OFF_IDX  2129921

// ---------------------------------------------------------------------------
// k_convprep: blocks 0..511 = conv (scalar-broadcast GEMV, no LDS);
//             512..639 zero sampled; 640..655 codebook norms + contrastive.
// conv: z[b,o,p] = sum_c W[o,c]*x[b,c,p] + bias[o]; lane = pixel (coalesced),
// wave w handles o = 16w..16w+15; c strictly ascending single-acc fmaf.
__global__ __launch_bounds__(256, 2) void k_convprep(const float* __restrict__ x,
                                                     const float* __restrict__ w,
                                                     const float* __restrict__ bias,
                                                     float* __restrict__ z,
                                                     float* __restrict__ out_samp,
                                                     const float* __restrict__ emb,
                                                     float* __restrict__ enorm,
                                                     float* __restrict__ cpart) {
    int bid = blockIdx.x, t = threadIdx.x;
    if (bid >= 512) {
        int pb = bid - 512;
        if (pb < 128) {
            out_samp[pb * 256 + t] = 0.0f;
            return;
        }
        int g = pb - 128;                   // 0..15, 64 codes each
        __shared__ float inv_s[64];
        __shared__ float S[256];
        if (t < 64) {
            int j = g * 64 + t;
            const float* e = emb + (size_t)j * ED;
            float r8[8];
            #pragma unroll
            for (int s = 0; s < 8; s++) { float v = e[s]; r8[s] = v * v; }
            #pragma unroll
            for (int m = 1; m < 8; m++) {
                #pragma unroll
                for (int s = 0; s < 8; s++) { float v = e[8 * m + s]; r8[s] += v * v; }
            }
            float en = ((r8[0] + r8[1]) + (r8[2] + r8[3])) + ((r8[4] + r8[5]) + (r8[6] + r8[7]));
            enorm[j] = en;
            inv_s[t] = 1.0f / sqrtf(en);
        }
        __syncthreads();
        int d = t & 63, q = t >> 6;
        float s = 0.0f;
        #pragma unroll
        for (int m = 0; m < 16; m++) {
            int i = q + 4 * m;
            s = fmaf(emb[(size_t)(g * 64 + i) * ED + d], inv_s[i], s);
        }
        S[t] = s;
        __syncthreads();
        if (t < 64)
            cpart[g * 64 + t] = (S[t] + S[t + 64]) + (S[t + 128] + S[t + 192]);
        return;
    }

    // ---- conv ----
    int b    = bid >> 4;
    int p    = ((bid & 15) << 6) + (t & 63);
    int wid  = __builtin_amdgcn_readfirstlane(t >> 6);   // uniform wave id
    const float* xb = x + ((size_t)b << 18) + p;         // x[b][c][p], c-stride 1024

    float acc[16];
    #pragma unroll
    for (int i = 0; i < 16; i++) acc[i] = 0.0f;

    for (int ch = 0; ch < 4; ch++) {
        int c0 = ch * 64;
        float xr[64];
        #pragma unroll
        for (int cc = 0; cc < 64; cc++) xr[cc] = xb[(size_t)(c0 + cc) << 10];
        #pragma unroll
        for (int op = 0; op < 8; op++) {
            int oa = wid * 16 + 2 * op;
            const float* wa = w + ((size_t)oa << 8) + c0;
            const float* wb = wa + 256;
            float da = acc[2 * op], db = acc[2 * op + 1];
            #pragma unroll
            for (int cc = 0; cc < 64; cc++) {
                da = fmaf(xr[cc], wa[cc], da);
                db = fmaf(xr[cc], wb[cc], db);
            }
            acc[2 * op] = da; acc[2 * op + 1] = db;
        }
    }
    #pragma unroll
    for (int oo = 0; oo < 16; oo++) {
        int o = wid * 16 + oo;
        z[((size_t)(b * 64 + o) << 10) + p] = acc[oo] + bias[o];
    }
}

// ---------------------------------------------------------------------------
// k_dist v2: lane = row (64 rows/block in registers), wave w scans codes
// [256w, 256w+256). Wave-uniform e addresses -> broadcast/scalar loads; no
// LDS in the hot loop (R4 post-mortem: LDS pipe = 12 cyc/b128 per CU was the
// 94us wall). Running argmin only -> no accumulator array. 4 codes in flight.
__global__ __launch_bounds__(256, 2) void k_dist(const float* __restrict__ z,
                                                 const float* __restrict__ emb,
                                                 const float* __restrict__ enorm,
                                                 float* __restrict__ out_idx,
                                                 float* __restrict__ out_samp,
                                                 float* __restrict__ out_zq,
                                                 float* __restrict__ ssep) {
    __shared__ float bd_s[4][64];
    __shared__ int   bj_s[4][64];
    int t    = threadIdx.x;
    int lane = t & 63;
    int wid  = __builtin_amdgcn_readfirstlane(t >> 6);
    int row  = blockIdx.x * 64 + lane;

    // whole z-row in registers (one-time load, L1/L2 shared across 4 waves)
    float zf[64];
    {
        const float* zr = z + ((size_t)row << 6);
        #pragma unroll
        for (int q = 0; q < 16; q++)
            *(float4*)&zf[4 * q] = *(const float4*)&zr[4 * q];
    }

    // zn: numpy-pairwise sum of squares (same code as prior passing rounds)
    float zn;
    {
        float r8[8];
        #pragma unroll
        for (int s = 0; s < 8; s++) { float v = zf[s]; r8[s] = v * v; }
        #pragma unroll
        for (int m = 1; m < 8; m++) {
            #pragma unroll
            for (int s = 0; s < 8; s++) { float v = zf[8 * m + s]; r8[s] += v * v; }
        }
        zn = ((r8[0] + r8[1]) + (r8[2] + r8[3])) + ((r8[4] + r8[5]) + (r8[6] + r8[7]));
    }

    int   cbase = wid << 8;
    const float* eb = emb + ((size_t)cbase << 6);
    float bestd = __builtin_huge_valf();
    int   bestj = 0;

    for (int cc = 0; cc < 256; cc += 4) {
        const float* e0 = eb + ((size_t)cc << 6);
        const float* e1 = e0 + 64;
        const float* e2 = e0 + 128;
        const float* e3 = e0 + 192;
        float d0 = 0.f, d1 = 0.f, d2 = 0.f, d3 = 0.f;
        #pragma unroll
        for (int k = 0; k < 64; k++) {          // strict ascending-k chains
            float zv = zf[k];
            d0 = fmaf(zv, e0[k], d0);
            d1 = fmaf(zv, e1[k], d1);
            d2 = fmaf(zv, e2[k], d2);
            d3 = fmaf(zv, e3[k], d3);
        }
        float en0 = enorm[cbase + cc];
        float en1 = enorm[cbase + cc + 1];
        float en2 = enorm[cbase + cc + 2];
        float en3 = enorm[cbase + cc + 3];
        // d = fl(fl(zn+en) - 2*dot); ascending c with strict < keeps first-min
        float A0 = zn + en0, D0 = A0 - 2.0f * d0;
        if (D0 < bestd) { bestd = D0; bestj = cbase + cc; }
        float A1 = zn + en1, D1 = A1 - 2.0f * d1;
        if (D1 < bestd) { bestd = D1; bestj = cbase + cc + 1; }
        float A2 = zn + en2, D2 = A2 - 2.0f * d2;
        if (D2 < bestd) { bestd = D2; bestj = cbase + cc + 2; }
        float A3 = zn + en3, D3 = A3 - 2.0f * d3;
        if (D3 < bestd) { bestd = D3; bestj = cbase + cc + 3; }
    }

    bd_s[wid][lane] = bestd;
    bj_s[wid][lane] = bestj;
    __syncthreads();

    if (t < 64) {       // wave 0: final argmin, outputs, fused STE + SSE
        float bd = bd_s[0][lane];
        int   bj = bj_s[0][lane];
        #pragma unroll
        for (int w2 = 1; w2 < 4; w2++) {        // ascending code chunks:
            float dd = bd_s[w2][lane];          // strict < keeps first-min
            int   jj = bj_s[w2][lane];
            if (dd < bd) { bd = dd; bj = jj; }
        }
        out_idx[row] = (float)bj;
        atomicExch(&out_samp[bj], 1.0f);        // scattered, low contention

        const float* ebest = emb + ((size_t)bj << 6);
        float* oz = out_zq + ((size_t)row << 6);
        float sq = 0.0f;
        #pragma unroll
        for (int q = 0; q < 16; q++) {
            float4 ev = *(const float4*)&ebest[4 * q];
            float dd0 = ev.x - zf[4 * q + 0];
            float dd1 = ev.y - zf[4 * q + 1];
            float dd2 = ev.z - zf[4 * q + 2];
            float dd3 = ev.w - zf[4 * q + 3];
            float4 o4;
            o4.x = zf[4 * q + 0] + dd0;
            o4.y = zf[4 * q + 1] + dd1;
            o4.z = zf[4 * q + 2] + dd2;
            o4.w = zf[4 * q + 3] + dd3;
            *(float4*)&oz[4 * q] = o4;
            sq += dd0 * dd0; sq += dd1 * dd1; sq += dd2 * dd2; sq += dd3 * dd3;
        }
        #pragma unroll
        for (int off = 32; off > 0; off >>= 1) sq += __shfl_down(sq, off, 64);
        if (lane == 0) ssep[blockIdx.x] = sq;
    }
}

// ---------------------------------------------------------------------------
// k_final: deterministic combine of 512 SSE partials + 16x64 contrastive.
__global__ __launch_bounds__(256) void k_final(const float* __restrict__ ssep,
                                               const float* __restrict__ cpart,
                                               float* __restrict__ out_loss) {
    __shared__ double SD[256];
    __shared__ float  CS;
    int t = threadIdx.x;
    SD[t] = (double)ssep[t] + (double)ssep[t + 256];
    __syncthreads();
    #pragma unroll
    for (int off = 128; off > 0; off >>= 1) {
        if (t < off) SD[t] += SD[t + off];
        __syncthreads();
    }
    if (t < 64) {
        float v = 0.0f;
        #pragma unroll
        for (int m = 0; m < 16; m++) v += cpart[m * 64 + t];
        float sq = v * v;
        #pragma unroll
        for (int off = 32; off > 0; off >>= 1) sq += __shfl_down(sq, off, 64);
        if (t == 0) CS = sq / (1024.0f * 1024.0f);
    }
    __syncthreads();
    if (t == 0) {
        float m = (float)(SD[0] / (double)ZTOT);
        out_loss[0] = (m + 0.25f * m) + CS;     // LEGACY: mse + BETA*mse
    }
}

// ---------------------------------------------------------------------------
extern "C" void kernel_launch(void* const* d_in, const int* in_sizes, int n_in,
                              void* d_out, int out_size, void* d_ws, size_t ws_size,
                              hipStream_t stream) {
    (void)in_sizes; (void)n_in; (void)out_size; (void)ws_size;
    const float* z_     = (const float*)d_in[0];
    const float* conv_w = (const float*)d_in[1];
    const float* conv_b = (const float*)d_in[2];
    const float* emb    = (const float*)d_in[3];

    float* out      = (float*)d_out;
    float* out_zq   = out;
    float* out_loss = out + OFF_LOSS;
    float* out_samp = out + OFF_SAMP;
    float* out_idx  = out + OFF_IDX;

    char*   ws    = (char*)d_ws;
    float*  wz    = (float*)ws;                 // z, 8 MB
    float*  enorm = (float*)(ws + 8388608);     // 1024
    float*  cpart = enorm + 1024;               // 16*64
    float*  ssep  = cpart + 1024;               // 512

    k_convprep<<<656, 256, 0, stream>>>(z_, conv_w, conv_b, wz,
                                        out_samp, emb, enorm, cpart);
    k_dist    <<<512, 256, 0, stream>>>(wz, emb, enorm, out_idx, out_samp,
                                        out_zq, ssep);
    k_final   <<<1, 256, 0, stream>>>(ssep, cpart, out_loss);
}

// Round 6
// 176.978 us; speedup vs baseline: 1.4042x; 1.4042x over previous
//
#include <hip/hip_runtime.h>
#include <hip/hip_bf16.h>

// Problem constants
#define NE      1024
#define ED      64
#define ZTOT    2097152       // 32*64*1024
#define CIN     256
#define COUT    64
#define HW      1024

// d_out layout (floats): z_q_st[ZTOT], loss[1], sampled[32768], min_idx[32768]
#define OFF_LOSS 2097152
#define OFF_SAMP 2097153
#define OFF_IDX  2129921

#define XSTR 68     // conv LDS pad
#define TSTR 132    // dist LDS [k][*] stride (128 + 4)

// ---------------------------------------------------------------------------
// k_prep: 0..127 zero sampled; 128..143 norms + contrastive partials;
//         144..159 transpose emb -> embT[k][c] (straight copies, no rounding).
__global__ __launch_bounds__(256) void k_prep(float* __restrict__ out_samp,
                                              const float* __restrict__ emb,
                                              float* __restrict__ enorm,
                                              float* __restrict__ cpart,
                                              float* __restrict__ embT) {
    int bid = blockIdx.x, t = threadIdx.x;
    if (bid < 128) {
        out_samp[bid * 256 + t] = 0.0f;
        return;
    }
    if (bid < 144) {
        int g = bid - 128;                  // 0..15, 64 codes each
        __shared__ float inv_s[64];
        __shared__ float S[256];
        if (t < 64) {
            int j = g * 64 + t;
            const float* e = emb + (size_t)j * ED;
            float r8[8];
            #pragma unroll
            for (int s = 0; s < 8; s++) { float v = e[s]; r8[s] = v * v; }
            #pragma unroll
            for (int m = 1; m < 8; m++) {
                #pragma unroll
                for (int s = 0; s < 8; s++) { float v = e[8 * m + s]; r8[s] += v * v; }
            }
            float en = ((r8[0] + r8[1]) + (r8[2] + r8[3])) + ((r8[4] + r8[5]) + (r8[6] + r8[7]));
            enorm[j] = en;
            inv_s[t] = 1.0f / sqrtf(en);
        }
        __syncthreads();
        int d = t & 63, q = t >> 6;
        float s = 0.0f;
        #pragma unroll
        for (int m = 0; m < 16; m++) {
            int i = q + 4 * m;
            s = fmaf(emb[(size_t)(g * 64 + i) * ED + d], inv_s[i], s);
        }
        S[t] = s;
        __syncthreads();
        if (t < 64)
            cpart[g * 64 + t] = (S[t] + S[t + 64]) + (S[t + 128] + S[t + 192]);
        return;
    }
    // emb transpose tile: 64 codes x 64 k
    int g2 = bid - 144;                     // 0..15
    int c0 = g2 * 64;
    __shared__ float tl[64 * 68];
    {
        int cc = t >> 2, q = t & 3;         // 4 threads/code, 16 floats each
        const float* src = emb + ((size_t)(c0 + cc) << 6) + 16 * q;
        #pragma unroll
        for (int m = 0; m < 4; m++) {
            float4 v = *(const float4*)&src[4 * m];
            *(float4*)&tl[cc * 68 + 16 * q + 4 * m] = v;
        }
    }
    __syncthreads();
    {
        int k = t >> 2, uq = t & 3;         // 4 threads/k, 16 c each
        float* dst = embT + ((size_t)k << 10) + c0 + 16 * uq;
        #pragma unroll
        for (int m = 0; m < 4; m++) {
            int cc = 16 * uq + 4 * m;
            float4 v;
            v.x = tl[(cc + 0) * 68 + k];
            v.y = tl[(cc + 1) * 68 + k];
            v.z = tl[(cc + 2) * 68 + k];
            v.w = tl[(cc + 3) * 68 + k];
            *(float4*)&dst[4 * m] = v;
        }
    }
}

// ---------------------------------------------------------------------------
// k_conv (R2-proven, unchanged): z[b,o,p] = sum_c W[o,c]*x[b,c,p] + bias[o].
__global__ __launch_bounds__(256) void k_conv(const float* __restrict__ x,
                                              const float* __restrict__ w,
                                              const float* __restrict__ bias,
                                              float* __restrict__ z) {
    __shared__ float Xs[64 * XSTR];
    __shared__ float Ws[64 * XSTR];
    int t  = threadIdx.x;
    int b  = blockIdx.y;
    int p0 = blockIdx.x * 64;
    int pg = t & 15;        // px = 4*pg + i
    int og = t >> 4;        // o  = 4*og + j
    float acc[4][4];
    #pragma unroll
    for (int i = 0; i < 4; i++)
        #pragma unroll
        for (int j = 0; j < 4; j++) acc[i][j] = 0.0f;

    for (int c0 = 0; c0 < CIN; c0 += 64) {
        __syncthreads();
        {
            int u = t & 15, cg2 = t >> 4;
            #pragma unroll
            for (int m = 0; m < 4; m++) {
                int c = cg2 + 16 * m;
                float4 v = *(const float4*)&x[(size_t)(b * CIN + c0 + c) * HW + p0 + 4 * u];
                *(float4*)&Xs[c * XSTR + 4 * u] = v;
            }
            #pragma unroll
            for (int m = 0; m < 4; m++) {
                int o = cg2 + 16 * m;
                float4 v = *(const float4*)&w[o * CIN + c0 + 4 * u];
                Ws[(4 * u + 0) * XSTR + o] = v.x;
                Ws[(4 * u + 1) * XSTR + o] = v.y;
                Ws[(4 * u + 2) * XSTR + o] = v.z;
                Ws[(4 * u + 3) * XSTR + o] = v.w;
            }
        }
        __syncthreads();
        #pragma unroll 8
        for (int k = 0; k < 64; k++) {
            float4 xv = *(const float4*)&Xs[k * XSTR + 4 * pg];
            float4 wv = *(const float4*)&Ws[k * XSTR + 4 * og];
            float xa[4] = {xv.x, xv.y, xv.z, xv.w};
            float wb[4] = {wv.x, wv.y, wv.z, wv.w};
            #pragma unroll
            for (int i = 0; i < 4; i++)
                #pragma unroll
                for (int j = 0; j < 4; j++)
                    acc[i][j] = fmaf(xa[i], wb[j], acc[i][j]);
        }
    }
    #pragma unroll
    for (int j = 0; j < 4; j++) {
        int o = 4 * og + j;
        float bv = bias[o];
        float4 outv;
        outv.x = acc[0][j] + bv;
        outv.y = acc[1][j] + bv;
        outv.z = acc[2][j] + bv;
        outv.w = acc[3][j] + bv;
        *(float4*)&z[(size_t)(b * COUT + o) * HW + p0 + 4 * pg] = outv;
    }
}

// ---------------------------------------------------------------------------
// k_dist: 128 rows/block, micro 8 rows x 8 codes, both operands LDS [k][*].
// Per k: 4 ds_read_b128 (all offsets are immediates) + 64 FMA -> ratio 16.
// Model: 2.1M wave-b128 x 12cyc / 256 CU = 41 us LDS-bound floor.
__global__ __launch_bounds__(256, 2) void k_dist(const float* __restrict__ z,
                                                 const float* __restrict__ embT,
                                                 const float* __restrict__ emb,
                                                 const float* __restrict__ enorm,
                                                 float* __restrict__ out_idx,
                                                 float* __restrict__ out_samp,
                                                 float* __restrict__ out_zq,
                                                 float* __restrict__ ssep) {
    __shared__ float zs[64 * TSTR];     // 33.8 KB  [k][row 0..127]
    __shared__ float es[64 * TSTR];     // 33.8 KB  [k][code_local 0..127]
    __shared__ float zn_s[128];
    __shared__ float bwd[4 * 128];
    __shared__ int   bwj[4 * 128];
    __shared__ int   bj_s[128];
    __shared__ float warr[4];
    int t    = threadIdx.x;
    int row0 = blockIdx.x * 128;
    int rg   = t & 15;      // rows: 4rg..4rg+3 and 64+4rg..64+4rg+3
    int cg   = t >> 4;      // codes in chunk: 4cg..4cg+3 and 64+4cg..64+4cg+3

    // stage zs transposed: zs[k][r]; 2 threads per row, 32 k each
    {
        int r = t >> 1, kh = (t & 1) * 32;
        const float* zr = z + ((size_t)(row0 + r) << 6) + kh;
        #pragma unroll
        for (int m = 0; m < 8; m++) {
            float4 v = *(const float4*)&zr[4 * m];
            int k = kh + 4 * m;
            zs[(k + 0) * TSTR + r] = v.x;
            zs[(k + 1) * TSTR + r] = v.y;
            zs[(k + 2) * TSTR + r] = v.z;
            zs[(k + 3) * TSTR + r] = v.w;
        }
    }
    // zn: numpy-pairwise sum of squares per row
    if (t < 128) {
        const float* zr = z + ((size_t)(row0 + t) << 6);
        float r8[8];
        #pragma unroll
        for (int s = 0; s < 8; s++) { float v = zr[s]; r8[s] = v * v; }
        #pragma unroll
        for (int m = 1; m < 8; m++) {
            #pragma unroll
            for (int s = 0; s < 8; s++) { float v = zr[8 * m + s]; r8[s] += v * v; }
        }
        zn_s[t] = ((r8[0] + r8[1]) + (r8[2] + r8[3])) + ((r8[4] + r8[5]) + (r8[6] + r8[7]));
    }
    __syncthreads();

    float znr[8];
    #pragma unroll
    for (int i = 0; i < 8; i++)
        znr[i] = zn_s[4 * rg + (i & 3) + 64 * (i >> 2)];

    float bestd[8];
    int   bestj[8];
    #pragma unroll
    for (int i = 0; i < 8; i++) { bestd[i] = __builtin_huge_valf(); bestj[i] = 0x7fffffff; }

    for (int ch = 0; ch < 8; ch++) {
        __syncthreads();                    // protect es from prior readers
        {   // stage es chunk: straight copy from embT (4 threads/k, 32 c each)
            int k = t >> 2, uq = t & 3;
            const float* src = embT + ((size_t)k << 10) + ch * 128 + 32 * uq;
            float* dst = es + k * TSTR + 32 * uq;
            #pragma unroll
            for (int m = 0; m < 8; m++)
                *(float4*)&dst[4 * m] = *(const float4*)&src[4 * m];
        }
        __syncthreads();

        float acc[8][8];
        #pragma unroll
        for (int i = 0; i < 8; i++)
            #pragma unroll
            for (int j = 0; j < 8; j++) acc[i][j] = 0.0f;

        #pragma unroll 4
        for (int k = 0; k < 64; k++) {      // strict ascending-k fma chains
            float4 za1 = *(const float4*)&zs[k * TSTR + 4 * rg];
            float4 za2 = *(const float4*)&zs[k * TSTR + 64 + 4 * rg];
            float4 ev1 = *(const float4*)&es[k * TSTR + 4 * cg];
            float4 ev2 = *(const float4*)&es[k * TSTR + 64 + 4 * cg];
            float zr8[8] = {za1.x, za1.y, za1.z, za1.w, za2.x, za2.y, za2.z, za2.w};
            float er8[8] = {ev1.x, ev1.y, ev1.z, ev1.w, ev2.x, ev2.y, ev2.z, ev2.w};
            #pragma unroll
            for (int i = 0; i < 8; i++)
                #pragma unroll
                for (int j = 0; j < 8; j++)
                    acc[i][j] = fmaf(zr8[i], er8[j], acc[i][j]);
        }

        // d = fl(fl(zn+en) - 2*dot); thread codes ascend -> strict < = first-min
        #pragma unroll
        for (int j = 0; j < 8; j++) {
            int c = ch * 128 + 4 * cg + (j & 3) + 64 * (j >> 2);
            float en = enorm[c];
            #pragma unroll
            for (int i = 0; i < 8; i++) {
                float A = znr[i] + en;
                float D = A - 2.0f * acc[i][j];
                if (D < bestd[i]) { bestd[i] = D; bestj[i] = c; }
            }
        }
    }

    // wave-level reduce over the 4 cg-quads (lanes l, l+16, l+32, l+48 share rg)
    #pragma unroll
    for (int i = 0; i < 8; i++) {
        float d = bestd[i]; int j = bestj[i];
        float d2 = __shfl_down(d, 32, 64); int j2 = __shfl_down(j, 32, 64);
        if (d2 < d || (d2 == d && j2 < j)) { d = d2; j = j2; }
        d2 = __shfl_down(d, 16, 64); j2 = __shfl_down(j, 16, 64);
        if (d2 < d || (d2 == d && j2 < j)) { d = d2; j = j2; }
        if ((t & 63) < 16) {
            int rl = 4 * (t & 15) + (i & 3) + 64 * (i >> 2);
            bwd[(t >> 6) * 128 + rl] = d;
            bwj[(t >> 6) * 128 + rl] = j;
        }
    }
    __syncthreads();
    if (t < 128) {
        float bd = bwd[t]; int bj = bwj[t];
        #pragma unroll
        for (int w2 = 1; w2 < 4; w2++) {    // index tie-break: order-safe
            float dd = bwd[w2 * 128 + t];
            int   jj = bwj[w2 * 128 + t];
            if (dd < bd || (dd == bd && jj < bj)) { bd = dd; bj = jj; }
        }
        bj_s[t] = bj;
        out_idx[row0 + t] = (float)bj;
        atomicExch(&out_samp[bj], 1.0f);    // scattered, low contention
    }
    __syncthreads();

    // Fused STE epilogue from zs (bit-exact z); 2 threads/row, 32 k each
    {
        int rl = t & 127, kh = (t >> 7) * 32;
        int bj = bj_s[rl];
        const float* er = emb + ((size_t)bj << 6) + kh;
        float* oz = out_zq + ((size_t)(row0 + rl) << 6) + kh;
        float sq = 0.0f;
        #pragma unroll
        for (int m = 0; m < 8; m++) {
            float4 ev = *(const float4*)&er[4 * m];
            int k = kh + 4 * m;
            float z0 = zs[(k + 0) * TSTR + rl];
            float z1 = zs[(k + 1) * TSTR + rl];
            float z2 = zs[(k + 2) * TSTR + rl];
            float z3 = zs[(k + 3) * TSTR + rl];
            float d0 = ev.x - z0, d1 = ev.y - z1, d2 = ev.z - z2, d3 = ev.w - z3;
            float4 o4;
            o4.x = z0 + d0; o4.y = z1 + d1; o4.z = z2 + d2; o4.w = z3 + d3;
            *(float4*)&oz[4 * m] = o4;
            sq += d0 * d0; sq += d1 * d1; sq += d2 * d2; sq += d3 * d3;
        }
        #pragma unroll
        for (int off = 32; off > 0; off >>= 1) sq += __shfl_down(sq, off, 64);
        if ((t & 63) == 0) warr[t >> 6] = sq;
    }
    __syncthreads();
    if (t == 0)
        ssep[blockIdx.x] = (warr[0] + warr[1]) + (warr[2] + warr[3]);
}

// ---------------------------------------------------------------------------
// k_final: deterministic combine of 256 SSE partials + 16x64 contrastive.
__global__ __launch_bounds__(256) void k_final(const float* __restrict__ ssep,
                                               const float* __restrict__ cpart,
                                               float* __restrict__ out_loss) {
    __shared__ double SD[256];
    __shared__ float  CS;
    int t = threadIdx.x;
    SD[t] = (double)ssep[t];
    __syncthreads();
    #pragma unroll
    for (int off = 128; off > 0; off >>= 1) {
        if (t < off) SD[t] += SD[t + off];
        __syncthreads();
    }
    if (t < 64) {
        float v = 0.0f;
        #pragma unroll
        for (int m = 0; m < 16; m++) v += cpart[m * 64 + t];
        float sq = v * v;
        #pragma unroll
        for (int off = 32; off > 0; off >>= 1) sq += __shfl_down(sq, off, 64);
        if (t == 0) CS = sq / (1024.0f * 1024.0f);
    }
    __syncthreads();
    if (t == 0) {
        float m = (float)(SD[0] / (double)ZTOT);
        out_loss[0] = (m + 0.25f * m) + CS;     // LEGACY: mse + BETA*mse
    }
}

// ---------------------------------------------------------------------------
extern "C" void kernel_launch(void* const* d_in, const int* in_sizes, int n_in,
                              void* d_out, int out_size, void* d_ws, size_t ws_size,
                              hipStream_t stream) {
    (void)in_sizes; (void)n_in; (void)out_size; (void)ws_size;
    const float* z_     = (const float*)d_in[0];
    const float* conv_w = (const float*)d_in[1];
    const float* conv_b = (const float*)d_in[2];
    const float* emb    = (const float*)d_in[3];

    float* out      = (float*)d_out;
    float* out_zq   = out;
    float* out_loss = out + OFF_LOSS;
    float* out_samp = out + OFF_SAMP;
    float* out_idx  = out + OFF_IDX;

    float* ws    = (float*)d_ws;
    float* wz    = ws;                      // 2M floats (8 MB)
    float* embT  = ws + 2097152;            // 64 x 1024 (256 KB)
    float* enorm = ws + 2162688;            // 1024
    float* cpart = ws + 2163712;            // 1024
    float* ssep  = ws + 2164736;            // 256

    k_prep <<<160, 256, 0, stream>>>(out_samp, emb, enorm, cpart, embT);
    k_conv <<<dim3(16, 32), 256, 0, stream>>>(z_, conv_w, conv_b, wz);
    k_dist <<<256, 256, 0, stream>>>(wz, embT, emb, enorm, out_idx, out_samp,
                                     out_zq, ssep);
    k_final<<<1, 256, 0, stream>>>(ssep, cpart, out_loss);
}